// Round 14
// baseline (167.414 us; speedup 1.0000x reference)
//
#include <hip/hip_runtime.h>
#include <hip/hip_bf16.h>

// Problem constants
#define B_ 2
#define T_ 2048
#define C_ 1024
#define H_ 16
#define D_ 64
#define M_ROWS (B_ * T_)      // 4096
#define N_QKV (3 * C_)        // 3072
#define QKS (2 * C_)          // q/k buffer row stride = 2048

typedef __bf16 bf16x8 __attribute__((ext_vector_type(8)));
typedef float f32x4 __attribute__((ext_vector_type(4)));

// 0.125 (1/sqrt(64)) * log2(e): softmax in base-2, scale folded in.
#define SC 0.18033688011112042f

// async global->LDS, 16B per lane. LDS dest = wave-uniform base + lane*16.
__device__ __forceinline__ void gl_lds16(const __bf16* g, __bf16* l) {
    __builtin_amdgcn_global_load_lds(
        (const __attribute__((address_space(1))) unsigned int*)g,
        (__attribute__((address_space(3))) unsigned int*)l, 16, 0, 0);
}

// ---------------------------------------------------------------------------
// Merged pre-pass: blocks [0,2048) convert x -> xb (bf16);
// blocks [2048,3072) transpose+convert Wqkv/Wproj -> [N][K] bf16.
// ---------------------------------------------------------------------------
__global__ __launch_bounds__(256) void prep(
    const float* __restrict__ x, const float* __restrict__ Wqkv,
    const float* __restrict__ Wproj, __bf16* __restrict__ xb,
    __bf16* __restrict__ Wqkvt, __bf16* __restrict__ Wprojt)
{
    __shared__ __bf16 Ts[64 * 72];
    const int tid = threadIdx.x;
    int bid = blockIdx.x;

    if (bid < 2048) {
        int i = bid * 256 + tid;
        const float4* pp = (const float4*)(x + (size_t)i * 8);
        float4 a = pp[0], b = pp[1];
        __bf16 v[8] = {(__bf16)a.x, (__bf16)a.y, (__bf16)a.z, (__bf16)a.w,
                       (__bf16)b.x, (__bf16)b.y, (__bf16)b.z, (__bf16)b.w};
        *(uint4*)(xb + (size_t)i * 8) = *(uint4*)v;
        return;
    }
    bid -= 2048;
    const int kx = bid & 15;
    const int gy = bid >> 4;
    const float* W; __bf16* Wt; int N, n0;
    if (gy < 48) { W = Wqkv;  Wt = Wqkvt;  N = N_QKV; n0 = gy * 64; }
    else         { W = Wproj; Wt = Wprojt; N = C_;    n0 = (gy - 48) * 64; }
    const int k0 = kx * 64;
#pragma unroll
    for (int i = 0; i < 4; ++i) {
        int f = i * 256 + tid;
        int r = f >> 4, c4 = (f & 15) * 4;
        float4 v = *(const float4*)(W + (size_t)(k0 + r) * N + n0 + c4);
        Ts[(c4 + 0) * 72 + r] = (__bf16)v.x;
        Ts[(c4 + 1) * 72 + r] = (__bf16)v.y;
        Ts[(c4 + 2) * 72 + r] = (__bf16)v.z;
        Ts[(c4 + 3) * 72 + r] = (__bf16)v.w;
    }
    __syncthreads();
#pragma unroll
    for (int i = 0; i < 2; ++i) {
        int f = i * 256 + tid;
        int n = f >> 3, c8 = (f & 7) * 8;
        *(uint4*)(Wt + (size_t)(n0 + n) * C_ + k0 + c8) = *(const uint4*)&Ts[n * 72 + c8];
    }
}

// ---------------------------------------------------------------------------
// GEMM1 (fused): qkv = xb @ Wqkvt^T + bqkv.  128x64 tiles, 1536 blocks.
// v11: double-buffered LDS, ONE barrier per K-iter (the attn-proven
// structure) — prefetch of tile k+1 overlaps MFMA on tile k; barrier
// drains DMA that had a full compute phase to land. 48 KB -> 3 blocks/CU.
// ---------------------------------------------------------------------------
#define GBK 64

__global__ __launch_bounds__(256) void gemm_qkv(
    const __bf16* __restrict__ A, const __bf16* __restrict__ Bt,
    const float* __restrict__ bias, __bf16* __restrict__ qk,
    __bf16* __restrict__ vt)
{
    __shared__ __bf16 As[2][128 * GBK];
    __shared__ __bf16 Bs[2][64 * GBK];

    const int tid  = threadIdx.x;
    const int m0   = blockIdx.x * 128;
    const int n0   = blockIdx.y * 64;
    const int w    = tid >> 6;
    const int lane = tid & 63;
    const int quad = lane >> 4;
    const int l16  = lane & 15;
    const int wr   = (w >> 1) * 64;   // 2x2 wave grid, 64x32 each
    const int wc   = (w & 1) * 32;
    const int K = C_;
    const bool swap = (n0 < 2 * C_);   // block-uniform

    const int arow = w * 32 + (lane >> 3);
    const int brow = w * 16 + (lane >> 3);
    const int sseg = ((lane & 7) ^ (lane >> 3)) * 8;
    const __bf16* Ag = A + (size_t)(m0 + arow) * K + sseg;
    const __bf16* Bg = Bt + (size_t)(n0 + brow) * K + sseg;

    f32x4 acc[4][2] = {};

    // stage tile 0 into buffer 0
#pragma unroll
    for (int i = 0; i < 4; ++i)
        gl_lds16(Ag + (size_t)(i * 8) * K, &As[0][(w * 32 + i * 8) * GBK]);
#pragma unroll
    for (int i = 0; i < 2; ++i)
        gl_lds16(Bg + (size_t)(i * 8) * K, &Bs[0][(w * 16 + i * 8) * GBK]);
    __syncthreads();

    for (int it = 0; it < K / GBK; ++it) {
        const int buf = it & 1;
        // prefetch next tile into other buffer (async; drains at the barrier)
        if (it + 1 < K / GBK) {
            const int k1 = (it + 1) * GBK;
#pragma unroll
            for (int i = 0; i < 4; ++i)
                gl_lds16(Ag + k1 + (size_t)(i * 8) * K, &As[buf ^ 1][(w * 32 + i * 8) * GBK]);
#pragma unroll
            for (int i = 0; i < 2; ++i)
                gl_lds16(Bg + k1 + (size_t)(i * 8) * K, &Bs[buf ^ 1][(w * 16 + i * 8) * GBK]);
        }
#pragma unroll
        for (int kk = 0; kk < 2; ++kk) {
            bf16x8 af[4], bf[2];
#pragma unroll
            for (int mi = 0; mi < 4; ++mi)
                af[mi] = *(const bf16x8*)&As[buf][(wr + mi * 16 + l16) * GBK +
                                                 (((kk * 4 + quad) ^ (l16 & 7)) * 8)];
#pragma unroll
            for (int ni = 0; ni < 2; ++ni)
                bf[ni] = *(const bf16x8*)&Bs[buf][(wc + ni * 16 + l16) * GBK +
                                                 (((kk * 4 + quad) ^ (l16 & 7)) * 8)];
            if (swap) {
#pragma unroll
                for (int mi = 0; mi < 4; ++mi)
#pragma unroll
                    for (int ni = 0; ni < 2; ++ni)
                        acc[mi][ni] = __builtin_amdgcn_mfma_f32_16x16x32_bf16(
                            bf[ni], af[mi], acc[mi][ni], 0, 0, 0);
            } else {
#pragma unroll
                for (int mi = 0; mi < 4; ++mi)
#pragma unroll
                    for (int ni = 0; ni < 2; ++ni)
                        acc[mi][ni] = __builtin_amdgcn_mfma_f32_16x16x32_bf16(
                            af[mi], bf[ni], acc[mi][ni], 0, 0, 0);
            }
        }
        __syncthreads();   // cur buffer consumed; prefetched tile drained
    }

    if (swap) {
#pragma unroll
        for (int ni = 0; ni < 2; ++ni) {
            int colb = n0 + wc + ni * 16 + quad * 4;
            float4 bv = *(const float4*)&bias[colb];
#pragma unroll
            for (int mi = 0; mi < 4; ++mi) {
                int row = m0 + wr + mi * 16 + l16;
                __bf16 pb[4] = {(__bf16)(acc[mi][ni][0] + bv.x),
                                (__bf16)(acc[mi][ni][1] + bv.y),
                                (__bf16)(acc[mi][ni][2] + bv.z),
                                (__bf16)(acc[mi][ni][3] + bv.w)};
                *(uint2*)&qk[(size_t)row * QKS + colb] = *(uint2*)pb;
            }
        }
    } else {
        const int bb = m0 >> 11;
        const int tb = (m0 & (T_ - 1)) + wr;
#pragma unroll
        for (int mi = 0; mi < 4; ++mi) {
#pragma unroll
            for (int ni = 0; ni < 2; ++ni) {
                int col = n0 + wc + ni * 16 + l16;
                float bv = bias[col];
                int c = col - 2 * C_;
                int t0 = tb + mi * 16 + quad * 4;
                __bf16 pb[4];
#pragma unroll
                for (int r = 0; r < 4; ++r)
                    pb[r] = (__bf16)(acc[mi][ni][r] + bv);
                *(uint2*)&vt[((size_t)bb * C_ + c) * T_ + t0] = *(uint2*)pb;
            }
        }
    }
}

// ---------------------------------------------------------------------------
// GEMM2: out = att @ Wprojt^T + bproj (fp32 out). 64x64 tiles, 1024 blocks
// = 4/CU, 16 KB LDS. Swapped-operand MFMA -> float4 stores. (unchanged)
// ---------------------------------------------------------------------------
__global__ __launch_bounds__(256) void gemm_proj(
    const __bf16* __restrict__ A, const __bf16* __restrict__ Bt,
    const float* __restrict__ bias, float* __restrict__ C)
{
    __shared__ __bf16 As[64 * GBK];
    __shared__ __bf16 Bs[64 * GBK];

    const int tid  = threadIdx.x;
    const int m0   = blockIdx.x * 64;
    const int n0   = blockIdx.y * 64;
    const int w    = tid >> 6;
    const int lane = tid & 63;
    const int quad = lane >> 4;
    const int l16  = lane & 15;
    const int wr   = (w >> 1) * 32;   // 2x2 wave grid, 32x32 each
    const int wc   = (w & 1) * 32;
    const int K = C_, N = C_;

    const int srow = w * 16 + (lane >> 3);
    const int sseg = ((lane & 7) ^ (lane >> 3)) * 8;
    const __bf16* Ag = A + (size_t)(m0 + srow) * K + sseg;
    const __bf16* Bg = Bt + (size_t)(n0 + srow) * K + sseg;

    f32x4 acc[2][2] = {};

    for (int k0 = 0; k0 < K; k0 += GBK) {
#pragma unroll
        for (int i = 0; i < 2; ++i) {
            gl_lds16(Ag + k0 + (size_t)(i * 8) * K, &As[(w * 16 + i * 8) * GBK]);
            gl_lds16(Bg + k0 + (size_t)(i * 8) * K, &Bs[(w * 16 + i * 8) * GBK]);
        }
        __syncthreads();
#pragma unroll
        for (int kk = 0; kk < 2; ++kk) {
            bf16x8 af[2], bf[2];
#pragma unroll
            for (int mi = 0; mi < 2; ++mi)
                af[mi] = *(const bf16x8*)&As[(wr + mi * 16 + l16) * GBK +
                                             (((kk * 4 + quad) ^ (l16 & 7)) * 8)];
#pragma unroll
            for (int ni = 0; ni < 2; ++ni)
                bf[ni] = *(const bf16x8*)&Bs[(wc + ni * 16 + l16) * GBK +
                                             (((kk * 4 + quad) ^ (l16 & 7)) * 8)];
#pragma unroll
            for (int mi = 0; mi < 2; ++mi)
#pragma unroll
                for (int ni = 0; ni < 2; ++ni)
                    acc[mi][ni] = __builtin_amdgcn_mfma_f32_16x16x32_bf16(
                        bf[ni], af[mi], acc[mi][ni], 0, 0, 0);
        }
        __syncthreads();
    }

    // C^T layout: lane = row, regs = 4 consecutive cols -> float4 stores
#pragma unroll
    for (int ni = 0; ni < 2; ++ni) {
        int colb = n0 + wc + ni * 16 + quad * 4;
        float4 bv = *(const float4*)&bias[colb];
#pragma unroll
        for (int mi = 0; mi < 2; ++mi) {
            int row = m0 + wr + mi * 16 + l16;
            float4 o = {acc[mi][ni][0] + bv.x, acc[mi][ni][1] + bv.y,
                        acc[mi][ni][2] + bv.z, acc[mi][ni][3] + bv.w};
            *(float4*)&C[(size_t)row * N + colb] = o;
        }
    }
}

// ---------------------------------------------------------------------------
// Flash attention v10 (unchanged, R13-best): balance-by-construction qt
// map — 1024 blocks at 40 KB = exactly 4/CU, all co-resident; CU quad
// sums = 66 iter-units everywhere. XCD pin on x, Ps aliased onto Qs,
// no-max base-2 softmax, S^T trick, double-buffered K/V staging.
// ---------------------------------------------------------------------------
__global__ __launch_bounds__(256) void attn_kernel(
    const __bf16* __restrict__ qk, const __bf16* __restrict__ vt,
    __bf16* __restrict__ out)
{
    __shared__ __bf16 Qs[64 * 64];       // doubles as per-wave P after hoist
    __shared__ __bf16 KVs[4][64 * 64];   // K0,V0,K1,V1 (double buffer)

    const int tid  = threadIdx.x;
    const int bh   = blockIdx.x;          // 0..31 -> XCD = bh % 8 (pinned)
    const int y    = blockIdx.y;          // balanced qt map (see header)
    const int qt   = (y < 8) ? (31 - y) : (y < 16) ? (y - 8)
                   : (y < 24) ? y : (39 - y);
    const int b    = bh >> 4;
    const int h    = bh & 15;
    const int w    = tid >> 6;
    const int lane = tid & 63;
    const int quad = lane >> 4;
    const int l16  = lane & 15;
    const int lxor = l16 & 7;

    const int srow = lane >> 3;
    const int sseg = ((lane & 7) ^ srow) * 8;
    __bf16* Psw = &Qs[(w * 16) * 64];     // wave-private 16x64 region

    // ---- stage Q tile + K/V tile 0 ----
    {
        const __bf16* Qg = qk + (size_t)(b * T_ + qt * 64 + w * 16 + srow) * QKS
                         + (size_t)h * 64 + sseg;
        gl_lds16(Qg, &Qs[(w * 16) * 64]);
        gl_lds16(Qg + (size_t)8 * QKS, &Qs[(w * 16 + 8) * 64]);
        const __bf16* Kg = qk + (size_t)(b * T_ + w * 16 + srow) * QKS
                         + C_ + (size_t)h * 64 + sseg;
        gl_lds16(Kg, &KVs[0][(w * 16) * 64]);
        gl_lds16(Kg + (size_t)8 * QKS, &KVs[0][(w * 16 + 8) * 64]);
        const __bf16* Vg = vt + ((size_t)(b * H_ + h) * 64 + w * 16 + srow) * T_ + sseg;
        gl_lds16(Vg, &KVs[1][(w * 16) * 64]);
        gl_lds16(Vg + (size_t)8 * T_, &KVs[1][(w * 16 + 8) * 64]);
    }
    __syncthreads();

    // ---- hoist Q fragments; Qs becomes per-wave P storage ----
    bf16x8 qf[2];
#pragma unroll
    for (int kk = 0; kk < 2; ++kk)
        qf[kk] = *(const bf16x8*)&Qs[(w * 16 + l16) * 64 + (((kk * 4 + quad) ^ lxor) * 8)];

    f32x4 o[4] = {};
    float lacc = 0.f;

    for (int kt = 0; kt <= qt; ++kt) {
        const __bf16* Ks = KVs[(kt & 1) * 2];
        const __bf16* Vs = KVs[(kt & 1) * 2 + 1];

        if (kt < qt) {
            int nb = ((kt + 1) & 1) * 2;
            const __bf16* Kg = qk + (size_t)(b * T_ + (kt + 1) * 64 + w * 16 + srow) * QKS
                             + C_ + (size_t)h * 64 + sseg;
            gl_lds16(Kg, &KVs[nb][(w * 16) * 64]);
            gl_lds16(Kg + (size_t)8 * QKS, &KVs[nb][(w * 16 + 8) * 64]);
            const __bf16* Vg = vt + ((size_t)(b * H_ + h) * 64 + w * 16 + srow) * T_
                             + (kt + 1) * 64 + sseg;
            gl_lds16(Vg, &KVs[nb + 1][(w * 16) * 64]);
            gl_lds16(Vg + (size_t)8 * T_, &KVs[nb + 1][(w * 16 + 8) * 64]);
        }

        // ---- S^T = K Q^T ----
        f32x4 s[4] = {};
#pragma unroll
        for (int ni = 0; ni < 4; ++ni) {
#pragma unroll
            for (int kk = 0; kk < 2; ++kk) {
                bf16x8 kf = *(const bf16x8*)&Ks[(ni * 16 + l16) * 64 +
                                                (((kk * 4 + quad) ^ lxor) * 8)];
                s[ni] = __builtin_amdgcn_mfma_f32_16x16x32_bf16(kf, qf[kk], s[ni], 0, 0, 0);
            }
        }

        if (kt == qt) {
#pragma unroll
            for (int ni = 0; ni < 4; ++ni)
#pragma unroll
                for (int r = 0; r < 4; ++r)
                    if (ni * 16 + quad * 4 + r > w * 16 + l16) s[ni][r] = -3.0e38f;
        }

        // ---- p = 2^(s*SC); accumulate l; pack; write P ----
#pragma unroll
        for (int ni = 0; ni < 4; ++ni) {
            __bf16 pb[4];
#pragma unroll
            for (int r = 0; r < 4; ++r) {
                float pe = __builtin_amdgcn_exp2f(s[ni][r] * SC);
                lacc += pe;
                pb[r] = (__bf16)pe;
            }
            int seg = (ni * 2 + (quad >> 1)) ^ lxor;
            *(uint2*)&Psw[l16 * 64 + seg * 8 + (quad & 1) * 4] = *(uint2*)pb;
        }
        __threadfence_block();

        // ---- O += P V ----
        bf16x8 pf[2];
#pragma unroll
        for (int kk = 0; kk < 2; ++kk)
            pf[kk] = *(const bf16x8*)&Psw[l16 * 64 + (((kk * 4 + quad) ^ lxor) * 8)];
#pragma unroll
        for (int ni = 0; ni < 4; ++ni) {
#pragma unroll
            for (int kk = 0; kk < 2; ++kk) {
                bf16x8 vf = *(const bf16x8*)&Vs[(ni * 16 + l16) * 64 +
                                                (((kk * 4 + quad) ^ lxor) * 8)];
                o[ni] = __builtin_amdgcn_mfma_f32_16x16x32_bf16(pf[kk], vf, o[ni], 0, 0, 0);
            }
        }
        __syncthreads();
    }

    // ---- reduce l; epilogue ----
    lacc += __shfl_xor(lacc, 16, 64);
    lacc += __shfl_xor(lacc, 32, 64);
#pragma unroll
    for (int r = 0; r < 4; ++r) {
        float linv = 1.f / __shfl(lacc, quad * 4 + r, 64);
        int trow = qt * 64 + w * 16 + quad * 4 + r;
#pragma unroll
        for (int ni = 0; ni < 4; ++ni)
            out[((size_t)(b * T_ + trow)) * C_ + h * 64 + ni * 16 + l16] =
                (__bf16)(o[ni][r] * linv);
    }
}

// ---------------------------------------------------------------------------
extern "C" void kernel_launch(void* const* d_in, const int* in_sizes, int n_in,
                              void* d_out, int out_size, void* d_ws, size_t ws_size,
                              hipStream_t stream)
{
    const float* x     = (const float*)d_in[0];
    const float* Wqkv  = (const float*)d_in[1];
    const float* bqkv  = (const float*)d_in[2];
    const float* Wproj = (const float*)d_in[3];
    const float* bproj = (const float*)d_in[4];
    float* out = (float*)d_out;

    char* ws = (char*)d_ws;
    __bf16* xb     = (__bf16*)(ws);                 //  8 MB [4096,1024] (reused as att)
    __bf16* Wqkvt  = (__bf16*)(ws + (8u  << 20));   //  6 MB [3072,1024]
    __bf16* Wprojt = (__bf16*)(ws + (14u << 20));   //  2 MB [1024,1024]
    __bf16* qk     = (__bf16*)(ws + (16u << 20));   // 16 MB [4096,2048]
    __bf16* vt     = (__bf16*)(ws + (32u << 20));   //  8 MB [B*C,2048]
    __bf16* att    = xb;                            // alias: xb dead after GEMM1

    prep<<<3072, 256, 0, stream>>>(x, Wqkv, Wproj, xb, Wqkvt, Wprojt);

    gemm_qkv<<<dim3(M_ROWS / 128, N_QKV / 64), 256, 0, stream>>>(
        xb, Wqkvt, bqkv, qk, vt);

    // balanced qt map (every CU's resident quad sums to 66 iter-units)
    attn_kernel<<<dim3(32, 32), 256, 0, stream>>>(qk, vt, att);

    gemm_proj<<<dim3(M_ROWS / 64, C_ / 64), 256, 0, stream>>>(
        att, Wprojt, bproj, out);
}

// Round 15
// 164.237 us; speedup vs baseline: 1.0193x; 1.0193x over previous
//
#include <hip/hip_runtime.h>
#include <hip/hip_bf16.h>

// Problem constants
#define B_ 2
#define T_ 2048
#define C_ 1024
#define H_ 16
#define D_ 64
#define M_ROWS (B_ * T_)      // 4096
#define N_QKV (3 * C_)        // 3072
#define QKS (2 * C_)          // q/k buffer row stride = 2048

typedef __bf16 bf16x8 __attribute__((ext_vector_type(8)));
typedef float f32x4 __attribute__((ext_vector_type(4)));

// 0.125 (1/sqrt(64)) * log2(e): softmax in base-2, scale folded in.
#define SC 0.18033688011112042f

// async global->LDS, 16B per lane. LDS dest = wave-uniform base + lane*16.
__device__ __forceinline__ void gl_lds16(const __bf16* g, __bf16* l) {
    __builtin_amdgcn_global_load_lds(
        (const __attribute__((address_space(1))) unsigned int*)g,
        (__attribute__((address_space(3))) unsigned int*)l, 16, 0, 0);
}

// ---------------------------------------------------------------------------
// Merged pre-pass: blocks [0,2048) convert x -> xb (bf16);
// blocks [2048,3072) transpose+convert Wqkv/Wproj -> [N][K] bf16.
// ---------------------------------------------------------------------------
__global__ __launch_bounds__(256) void prep(
    const float* __restrict__ x, const float* __restrict__ Wqkv,
    const float* __restrict__ Wproj, __bf16* __restrict__ xb,
    __bf16* __restrict__ Wqkvt, __bf16* __restrict__ Wprojt)
{
    __shared__ __bf16 Ts[64 * 72];
    const int tid = threadIdx.x;
    int bid = blockIdx.x;

    if (bid < 2048) {
        int i = bid * 256 + tid;
        const float4* pp = (const float4*)(x + (size_t)i * 8);
        float4 a = pp[0], b = pp[1];
        __bf16 v[8] = {(__bf16)a.x, (__bf16)a.y, (__bf16)a.z, (__bf16)a.w,
                       (__bf16)b.x, (__bf16)b.y, (__bf16)b.z, (__bf16)b.w};
        *(uint4*)(xb + (size_t)i * 8) = *(uint4*)v;
        return;
    }
    bid -= 2048;
    const int kx = bid & 15;
    const int gy = bid >> 4;
    const float* W; __bf16* Wt; int N, n0;
    if (gy < 48) { W = Wqkv;  Wt = Wqkvt;  N = N_QKV; n0 = gy * 64; }
    else         { W = Wproj; Wt = Wprojt; N = C_;    n0 = (gy - 48) * 64; }
    const int k0 = kx * 64;
#pragma unroll
    for (int i = 0; i < 4; ++i) {
        int f = i * 256 + tid;
        int r = f >> 4, c4 = (f & 15) * 4;
        float4 v = *(const float4*)(W + (size_t)(k0 + r) * N + n0 + c4);
        Ts[(c4 + 0) * 72 + r] = (__bf16)v.x;
        Ts[(c4 + 1) * 72 + r] = (__bf16)v.y;
        Ts[(c4 + 2) * 72 + r] = (__bf16)v.z;
        Ts[(c4 + 3) * 72 + r] = (__bf16)v.w;
    }
    __syncthreads();
#pragma unroll
    for (int i = 0; i < 2; ++i) {
        int f = i * 256 + tid;
        int n = f >> 3, c8 = (f & 7) * 8;
        *(uint4*)(Wt + (size_t)(n0 + n) * C_ + k0 + c8) = *(const uint4*)&Ts[n * 72 + c8];
    }
}

// ---------------------------------------------------------------------------
// GEMM1 (fused): qkv = xb @ Wqkvt^T + bqkv.  128x64 tiles, 1536 blocks,
// 24 KB LDS -> 6 blocks/CU. R14's explicit double-buffer (48 KB, 3/CU)
// was neutral-to-negative — TLP beats intra-block pipelining here.
// q/k blocks: swapped-operand MFMA -> C^T layout -> uint2 stores.
// v blocks: original order -> transposed uint2 store into vt[(b*C+c)][t].
// ---------------------------------------------------------------------------
#define GBK 64

__global__ __launch_bounds__(256) void gemm_qkv(
    const __bf16* __restrict__ A, const __bf16* __restrict__ Bt,
    const float* __restrict__ bias, __bf16* __restrict__ qk,
    __bf16* __restrict__ vt)
{
    __shared__ __bf16 As[128 * GBK];
    __shared__ __bf16 Bs[64 * GBK];

    const int tid  = threadIdx.x;
    const int m0   = blockIdx.x * 128;
    const int n0   = blockIdx.y * 64;
    const int w    = tid >> 6;
    const int lane = tid & 63;
    const int quad = lane >> 4;
    const int l16  = lane & 15;
    const int wr   = (w >> 1) * 64;   // 2x2 wave grid, 64x32 each
    const int wc   = (w & 1) * 32;
    const int K = C_;
    const bool swap = (n0 < 2 * C_);   // block-uniform

    const int arow = w * 32 + (lane >> 3);
    const int brow = w * 16 + (lane >> 3);
    const int sseg = ((lane & 7) ^ (lane >> 3)) * 8;
    const __bf16* Ag = A + (size_t)(m0 + arow) * K + sseg;
    const __bf16* Bg = Bt + (size_t)(n0 + brow) * K + sseg;

    f32x4 acc[4][2] = {};

    for (int k0 = 0; k0 < K; k0 += GBK) {
#pragma unroll
        for (int i = 0; i < 4; ++i)
            gl_lds16(Ag + k0 + (size_t)(i * 8) * K, &As[(w * 32 + i * 8) * GBK]);
#pragma unroll
        for (int i = 0; i < 2; ++i)
            gl_lds16(Bg + k0 + (size_t)(i * 8) * K, &Bs[(w * 16 + i * 8) * GBK]);
        __syncthreads();
#pragma unroll
        for (int kk = 0; kk < 2; ++kk) {
            bf16x8 af[4], bf[2];
#pragma unroll
            for (int mi = 0; mi < 4; ++mi)
                af[mi] = *(const bf16x8*)&As[(wr + mi * 16 + l16) * GBK +
                                             (((kk * 4 + quad) ^ (l16 & 7)) * 8)];
#pragma unroll
            for (int ni = 0; ni < 2; ++ni)
                bf[ni] = *(const bf16x8*)&Bs[(wc + ni * 16 + l16) * GBK +
                                             (((kk * 4 + quad) ^ (l16 & 7)) * 8)];
            if (swap) {
#pragma unroll
                for (int mi = 0; mi < 4; ++mi)
#pragma unroll
                    for (int ni = 0; ni < 2; ++ni)
                        acc[mi][ni] = __builtin_amdgcn_mfma_f32_16x16x32_bf16(
                            bf[ni], af[mi], acc[mi][ni], 0, 0, 0);
            } else {
#pragma unroll
                for (int mi = 0; mi < 4; ++mi)
#pragma unroll
                    for (int ni = 0; ni < 2; ++ni)
                        acc[mi][ni] = __builtin_amdgcn_mfma_f32_16x16x32_bf16(
                            af[mi], bf[ni], acc[mi][ni], 0, 0, 0);
            }
        }
        __syncthreads();
    }

    if (swap) {
#pragma unroll
        for (int ni = 0; ni < 2; ++ni) {
            int colb = n0 + wc + ni * 16 + quad * 4;
            float4 bv = *(const float4*)&bias[colb];
#pragma unroll
            for (int mi = 0; mi < 4; ++mi) {
                int row = m0 + wr + mi * 16 + l16;
                __bf16 pb[4] = {(__bf16)(acc[mi][ni][0] + bv.x),
                                (__bf16)(acc[mi][ni][1] + bv.y),
                                (__bf16)(acc[mi][ni][2] + bv.z),
                                (__bf16)(acc[mi][ni][3] + bv.w)};
                *(uint2*)&qk[(size_t)row * QKS + colb] = *(uint2*)pb;
            }
        }
    } else {
        const int bb = m0 >> 11;
        const int tb = (m0 & (T_ - 1)) + wr;
#pragma unroll
        for (int mi = 0; mi < 4; ++mi) {
#pragma unroll
            for (int ni = 0; ni < 2; ++ni) {
                int col = n0 + wc + ni * 16 + l16;
                float bv = bias[col];
                int c = col - 2 * C_;
                int t0 = tb + mi * 16 + quad * 4;
                __bf16 pb[4];
#pragma unroll
                for (int r = 0; r < 4; ++r)
                    pb[r] = (__bf16)(acc[mi][ni][r] + bv);
                *(uint2*)&vt[((size_t)bb * C_ + c) * T_ + t0] = *(uint2*)pb;
            }
        }
    }
}

// ---------------------------------------------------------------------------
// GEMM2: out = att @ Wprojt^T + bproj (fp32 out). 64x64 tiles, 1024 blocks
// = 4/CU, 16 KB LDS. Swapped-operand MFMA -> float4 stores.
// ---------------------------------------------------------------------------
__global__ __launch_bounds__(256) void gemm_proj(
    const __bf16* __restrict__ A, const __bf16* __restrict__ Bt,
    const float* __restrict__ bias, float* __restrict__ C)
{
    __shared__ __bf16 As[64 * GBK];
    __shared__ __bf16 Bs[64 * GBK];

    const int tid  = threadIdx.x;
    const int m0   = blockIdx.x * 64;
    const int n0   = blockIdx.y * 64;
    const int w    = tid >> 6;
    const int lane = tid & 63;
    const int quad = lane >> 4;
    const int l16  = lane & 15;
    const int wr   = (w >> 1) * 32;   // 2x2 wave grid, 32x32 each
    const int wc   = (w & 1) * 32;
    const int K = C_, N = C_;

    const int srow = w * 16 + (lane >> 3);
    const int sseg = ((lane & 7) ^ (lane >> 3)) * 8;
    const __bf16* Ag = A + (size_t)(m0 + srow) * K + sseg;
    const __bf16* Bg = Bt + (size_t)(n0 + srow) * K + sseg;

    f32x4 acc[2][2] = {};

    for (int k0 = 0; k0 < K; k0 += GBK) {
#pragma unroll
        for (int i = 0; i < 2; ++i) {
            gl_lds16(Ag + k0 + (size_t)(i * 8) * K, &As[(w * 16 + i * 8) * GBK]);
            gl_lds16(Bg + k0 + (size_t)(i * 8) * K, &Bs[(w * 16 + i * 8) * GBK]);
        }
        __syncthreads();
#pragma unroll
        for (int kk = 0; kk < 2; ++kk) {
            bf16x8 af[2], bf[2];
#pragma unroll
            for (int mi = 0; mi < 2; ++mi)
                af[mi] = *(const bf16x8*)&As[(wr + mi * 16 + l16) * GBK +
                                             (((kk * 4 + quad) ^ (l16 & 7)) * 8)];
#pragma unroll
            for (int ni = 0; ni < 2; ++ni)
                bf[ni] = *(const bf16x8*)&Bs[(wc + ni * 16 + l16) * GBK +
                                             (((kk * 4 + quad) ^ (l16 & 7)) * 8)];
#pragma unroll
            for (int mi = 0; mi < 2; ++mi)
#pragma unroll
                for (int ni = 0; ni < 2; ++ni)
                    acc[mi][ni] = __builtin_amdgcn_mfma_f32_16x16x32_bf16(
                        bf[ni], af[mi], acc[mi][ni], 0, 0, 0);
        }
        __syncthreads();
    }

    // C^T layout: lane = row, regs = 4 consecutive cols -> float4 stores
#pragma unroll
    for (int ni = 0; ni < 2; ++ni) {
        int colb = n0 + wc + ni * 16 + quad * 4;
        float4 bv = *(const float4*)&bias[colb];
#pragma unroll
        for (int mi = 0; mi < 2; ++mi) {
            int row = m0 + wr + mi * 16 + l16;
            float4 o = {acc[mi][ni][0] + bv.x, acc[mi][ni][1] + bv.y,
                        acc[mi][ni][2] + bv.z, acc[mi][ni][3] + bv.w};
            *(float4*)&C[(size_t)row * N + colb] = o;
        }
    }
}

// ---------------------------------------------------------------------------
// Flash attention v10 (R13-best, unchanged): balance-by-construction qt
// map — 1024 blocks at 40 KB = exactly 4/CU, all co-resident; CU quad
// sums = 66 iter-units everywhere. XCD pin on x, Ps aliased onto Qs,
// no-max base-2 softmax, S^T trick, double-buffered K/V staging.
// ---------------------------------------------------------------------------
__global__ __launch_bounds__(256) void attn_kernel(
    const __bf16* __restrict__ qk, const __bf16* __restrict__ vt,
    __bf16* __restrict__ out)
{
    __shared__ __bf16 Qs[64 * 64];       // doubles as per-wave P after hoist
    __shared__ __bf16 KVs[4][64 * 64];   // K0,V0,K1,V1 (double buffer)

    const int tid  = threadIdx.x;
    const int bh   = blockIdx.x;          // 0..31 -> XCD = bh % 8 (pinned)
    const int y    = blockIdx.y;          // balanced qt map (see header)
    const int qt   = (y < 8) ? (31 - y) : (y < 16) ? (y - 8)
                   : (y < 24) ? y : (39 - y);
    const int b    = bh >> 4;
    const int h    = bh & 15;
    const int w    = tid >> 6;
    const int lane = tid & 63;
    const int quad = lane >> 4;
    const int l16  = lane & 15;
    const int lxor = l16 & 7;

    const int srow = lane >> 3;
    const int sseg = ((lane & 7) ^ srow) * 8;
    __bf16* Psw = &Qs[(w * 16) * 64];     // wave-private 16x64 region

    // ---- stage Q tile + K/V tile 0 ----
    {
        const __bf16* Qg = qk + (size_t)(b * T_ + qt * 64 + w * 16 + srow) * QKS
                         + (size_t)h * 64 + sseg;
        gl_lds16(Qg, &Qs[(w * 16) * 64]);
        gl_lds16(Qg + (size_t)8 * QKS, &Qs[(w * 16 + 8) * 64]);
        const __bf16* Kg = qk + (size_t)(b * T_ + w * 16 + srow) * QKS
                         + C_ + (size_t)h * 64 + sseg;
        gl_lds16(Kg, &KVs[0][(w * 16) * 64]);
        gl_lds16(Kg + (size_t)8 * QKS, &KVs[0][(w * 16 + 8) * 64]);
        const __bf16* Vg = vt + ((size_t)(b * H_ + h) * 64 + w * 16 + srow) * T_ + sseg;
        gl_lds16(Vg, &KVs[1][(w * 16) * 64]);
        gl_lds16(Vg + (size_t)8 * T_, &KVs[1][(w * 16 + 8) * 64]);
    }
    __syncthreads();

    // ---- hoist Q fragments; Qs becomes per-wave P storage ----
    bf16x8 qf[2];
#pragma unroll
    for (int kk = 0; kk < 2; ++kk)
        qf[kk] = *(const bf16x8*)&Qs[(w * 16 + l16) * 64 + (((kk * 4 + quad) ^ lxor) * 8)];

    f32x4 o[4] = {};
    float lacc = 0.f;

    for (int kt = 0; kt <= qt; ++kt) {
        const __bf16* Ks = KVs[(kt & 1) * 2];
        const __bf16* Vs = KVs[(kt & 1) * 2 + 1];

        if (kt < qt) {
            int nb = ((kt + 1) & 1) * 2;
            const __bf16* Kg = qk + (size_t)(b * T_ + (kt + 1) * 64 + w * 16 + srow) * QKS
                             + C_ + (size_t)h * 64 + sseg;
            gl_lds16(Kg, &KVs[nb][(w * 16) * 64]);
            gl_lds16(Kg + (size_t)8 * QKS, &KVs[nb][(w * 16 + 8) * 64]);
            const __bf16* Vg = vt + ((size_t)(b * H_ + h) * 64 + w * 16 + srow) * T_
                             + (kt + 1) * 64 + sseg;
            gl_lds16(Vg, &KVs[nb + 1][(w * 16) * 64]);
            gl_lds16(Vg + (size_t)8 * T_, &KVs[nb + 1][(w * 16 + 8) * 64]);
        }

        // ---- S^T = K Q^T ----
        f32x4 s[4] = {};
#pragma unroll
        for (int ni = 0; ni < 4; ++ni) {
#pragma unroll
            for (int kk = 0; kk < 2; ++kk) {
                bf16x8 kf = *(const bf16x8*)&Ks[(ni * 16 + l16) * 64 +
                                                (((kk * 4 + quad) ^ lxor) * 8)];
                s[ni] = __builtin_amdgcn_mfma_f32_16x16x32_bf16(kf, qf[kk], s[ni], 0, 0, 0);
            }
        }

        if (kt == qt) {
#pragma unroll
            for (int ni = 0; ni < 4; ++ni)
#pragma unroll
                for (int r = 0; r < 4; ++r)
                    if (ni * 16 + quad * 4 + r > w * 16 + l16) s[ni][r] = -3.0e38f;
        }

        // ---- p = 2^(s*SC); accumulate l; pack; write P ----
#pragma unroll
        for (int ni = 0; ni < 4; ++ni) {
            __bf16 pb[4];
#pragma unroll
            for (int r = 0; r < 4; ++r) {
                float pe = __builtin_amdgcn_exp2f(s[ni][r] * SC);
                lacc += pe;
                pb[r] = (__bf16)pe;
            }
            int seg = (ni * 2 + (quad >> 1)) ^ lxor;
            *(uint2*)&Psw[l16 * 64 + seg * 8 + (quad & 1) * 4] = *(uint2*)pb;
        }
        __threadfence_block();

        // ---- O += P V ----
        bf16x8 pf[2];
#pragma unroll
        for (int kk = 0; kk < 2; ++kk)
            pf[kk] = *(const bf16x8*)&Psw[l16 * 64 + (((kk * 4 + quad) ^ lxor) * 8)];
#pragma unroll
        for (int ni = 0; ni < 4; ++ni) {
#pragma unroll
            for (int kk = 0; kk < 2; ++kk) {
                bf16x8 vf = *(const bf16x8*)&Vs[(ni * 16 + l16) * 64 +
                                                (((kk * 4 + quad) ^ lxor) * 8)];
                o[ni] = __builtin_amdgcn_mfma_f32_16x16x32_bf16(pf[kk], vf, o[ni], 0, 0, 0);
            }
        }
        __syncthreads();
    }

    // ---- reduce l; epilogue ----
    lacc += __shfl_xor(lacc, 16, 64);
    lacc += __shfl_xor(lacc, 32, 64);
#pragma unroll
    for (int r = 0; r < 4; ++r) {
        float linv = 1.f / __shfl(lacc, quad * 4 + r, 64);
        int trow = qt * 64 + w * 16 + quad * 4 + r;
#pragma unroll
        for (int ni = 0; ni < 4; ++ni)
            out[((size_t)(b * T_ + trow)) * C_ + h * 64 + ni * 16 + l16] =
                (__bf16)(o[ni][r] * linv);
    }
}

// ---------------------------------------------------------------------------
extern "C" void kernel_launch(void* const* d_in, const int* in_sizes, int n_in,
                              void* d_out, int out_size, void* d_ws, size_t ws_size,
                              hipStream_t stream)
{
    const float* x     = (const float*)d_in[0];
    const float* Wqkv  = (const float*)d_in[1];
    const float* bqkv  = (const float*)d_in[2];
    const float* Wproj = (const float*)d_in[3];
    const float* bproj = (const float*)d_in[4];
    float* out = (float*)d_out;

    char* ws = (char*)d_ws;
    __bf16* xb     = (__bf16*)(ws);                 //  8 MB [4096,1024] (reused as att)
    __bf16* Wqkvt  = (__bf16*)(ws + (8u  << 20));   //  6 MB [3072,1024]
    __bf16* Wprojt = (__bf16*)(ws + (14u << 20));   //  2 MB [1024,1024]
    __bf16* qk     = (__bf16*)(ws + (16u << 20));   // 16 MB [4096,2048]
    __bf16* vt     = (__bf16*)(ws + (32u << 20));   //  8 MB [B*C,2048]
    __bf16* att    = xb;                            // alias: xb dead after GEMM1

    prep<<<3072, 256, 0, stream>>>(x, Wqkv, Wproj, xb, Wqkvt, Wprojt);

    gemm_qkv<<<dim3(M_ROWS / 128, N_QKV / 64), 256, 0, stream>>>(
        xb, Wqkvt, bqkv, qk, vt);

    // balanced qt map (every CU's resident quad sums to 66 iter-units)
    attn_kernel<<<dim3(32, 32), 256, 0, stream>>>(qk, vt, att);

    gemm_proj<<<dim3(M_ROWS / 64, C_ / 64), 256, 0, stream>>>(
        att, Wprojt, bproj, out);
}